// Round 14
// baseline (1188.868 us; speedup 1.0000x reference)
//
#include <hip/hip_runtime.h>
#include <math.h>

#define NB 8
#define NN 4096
#define DD 256
#define CC 1024
#define NQ 8
#define ROWS (NB*NN)        // 32768
// fp16 1-pass: score = cn2 - 2*hi_a·hi_e, K=256.
// Dropped terms (hi_a·lo_e + lo_a·e): pair-difference score err std ~9e-3.
// TAU = 0.0625 ~ 7 sigma; flagged rows get exact fp32 re-argmin.
#define TAU 0.0625f

typedef unsigned short u16;
typedef __attribute__((ext_vector_type(8))) _Float16 f16x8;  // 8 f16 (4 VGPRs)
typedef __attribute__((ext_vector_type(4))) float f32x4;

// ---- exact RNE fp32->fp16 helpers (v_cvt_f16_f32 is RNE) ----
__device__ __forceinline__ u16 f2h(float f) {
  _Float16 h = (_Float16)f;
  return __builtin_bit_cast(u16, h);
}
__device__ __forceinline__ void hi4h(float4 f, ushort4& h) {
  h.x = f2h(f.x); h.y = f2h(f.y); h.z = f2h(f.z); h.w = f2h(f.w);
}

// merge candidate pair (w1,d1)<=(w2,d2) into running sorted top-2
__device__ __forceinline__ void merge_top2(float& v1, float& c1, float& v2, float& c2,
                                           float w1, float d1, float w2, float d2) {
  if (w1 < v1 || (w1 == v1 && d1 < c1)) {
    float nv2, nc2;
    if (v1 < w2 || (v1 == w2 && c1 < d2)) { nv2 = v1; nc2 = c1; }
    else                                  { nv2 = w2; nc2 = d2; }
    v1 = w1; c1 = d1; v2 = nv2; c2 = nc2;
  } else {
    if (w1 < v2 || (w1 == v2 && d1 < c2)) { v2 = w1; c2 = d1; }
  }
}

__device__ __forceinline__ void gload16(const void* g, void* l) {
  __builtin_amdgcn_global_load_lds(
      (const __attribute__((address_space(1))) unsigned int*)g,
      (__attribute__((address_space(3))) unsigned int*)l, 16, 0, 0);
}

// ---------------------------------------------------------------------------
// fused preamble: x -> rsplit [ROWS][256] fp16 hi  (blocks 0..8191)
//                 cb -> esp [NQ*CC][256] fp16 hi   (blocks 8192..10239)
// block 0 also zeroes cnt + loss_out (loss is atomically accumulated now).
// ---------------------------------------------------------------------------
__global__ __launch_bounds__(256) void rvq_pre(
    const float* __restrict__ x, const float* __restrict__ cb,
    u16* __restrict__ rsplit, u16* __restrict__ esp,
    int* __restrict__ cnt, float* __restrict__ loss_out)
{
  if (blockIdx.x == 0 && threadIdx.x < 64 + NQ) {
    if (threadIdx.x < 64) loss_out[threadIdx.x] = 0.f;   // NB*NQ = 64
    else cnt[threadIdx.x - 64] = 0;
  }
  const size_t f = (size_t)blockIdx.x * 256 + threadIdx.x;
  if (f < (size_t)ROWS * 64) {                 // x region: 2M float4
    const size_t row = f >> 6;
    const int c4 = (int)(f & 63) << 2;
    float4 v = ((const float4*)x)[f];
    ushort4 h; hi4h(v, h);
    *(ushort4*)(rsplit + row * 256 + c4) = h;
  } else {                                     // cb region: 512K float4
    const size_t g = f - (size_t)ROWS * 64;
    const size_t row = g >> 6;
    const int c4 = (int)(g & 63) << 2;
    float4 v = ((const float4*)cb)[g];
    ushort4 h; hi4h(v, h);
    *(ushort4*)(esp + row * 256 + c4) = h;
  }
}

// ---------------------------------------------------------------------------
// ||e_c||^2 for all levels (fp32), one wave per code
// ---------------------------------------------------------------------------
__global__ __launch_bounds__(256) void rvq_norms(
    const float* __restrict__ cb, float* __restrict__ cn2)
{
  const int tid = threadIdx.x;
  const size_t code = (size_t)blockIdx.x * 4 + (tid >> 6);
  const int l = tid & 63;
  const float4 v = *reinterpret_cast<const float4*>(cb + code * DD + l * 4);
  float s = v.x * v.x + v.y * v.y + v.z * v.z + v.w * v.w;
  #pragma unroll
  for (int mm = 1; mm < 64; mm <<= 1) s += __shfl_xor(s, mm);
  if (l == 0) cn2[code] = s;
}

// ---------------------------------------------------------------------------
// MFMA GEMM + per-block top2.  fp16 hi x hi, K=256, BK=32, 8 steps.
// R12-verified: BM=128 BN=128, acc[4][4], triple-buffer gload_lds, counted
// vmcnt(4), T2 swizzle (conflicts==0), XCD decode, epilogue v2.
// ---------------------------------------------------------------------------
__global__ __launch_bounds__(256) void rvq_gemm97(
    const u16* __restrict__ rsplit,   // [ROWS][256]  fp16 hi
    const u16* __restrict__ esp,      // [CC][256]    fp16 hi (level)
    const float* __restrict__ cn2q,   // [CC]         (level)
    float4* __restrict__ top2)        // [ROWS][8]
{
  // single 48 KB arena: As[3] at 0..24KB, Bs[3] at 24..48KB; epilogue reuses
  __shared__ __align__(16) u16 shm[24576];
  #define AS(c) (shm + (c) * 4096)
  #define BS(c) (shm + 12288 + (c) * 4096)

  const int tid = threadIdx.x;
  const int lane = tid & 63;
  const int wv = tid >> 6;
  const int wr = wv >> 1, wc = wv & 1;
  const int fr = lane & 15, fg = lane >> 4;
  // XCD-locality decode: bid = mbhi*64 + nb*8 + (mb%8)
  const int bid = blockIdx.x;
  const int mb = ((bid >> 6) << 3) | (bid & 7);
  const int nb = (bid >> 3) & 7;
  const size_t row0 = (size_t)mb * 128;

  // ---- T2: swizzled per-lane source slot for staging (LDS dest is linear) ----
  const int jl = lane ^ ((lane >> 3) & 3);   // logical slot this lane must fetch
  const int lrow = jl >> 2;                  // row within 16-row region
  const int lc4 = jl & 3;                    // 16B k-chunk within row

  // ---- T2: swizzled LDS offset for fragment reads (u16 units) ----
  const int j = (fr << 2) + fg;              // logical slot (row fr, k-chunk fg)
  const int js8 = (j ^ ((j >> 3) & 3)) << 3; // swizzled, *8 u16 per 16B slot

  auto stage = [&](int t, int cur) {
    const int o = (t & 7) << 5;               // k-chunk (u16) within 256
    #pragma unroll
    for (int r = 0; r < 2; ++r) {
      const int r0 = ((r << 2) + wv) << 4;                    // region first row
      const int grow = r0 + lrow;
      gload16(rsplit + (row0 + grow) * 256 + o + (lc4 << 3), AS(cur) + r0 * 32);
      gload16(esp + (size_t)(nb * 128 + grow) * 256 + o + (lc4 << 3), BS(cur) + r0 * 32);
    }
  };

  f32x4 acc[4][4];
  #pragma unroll
  for (int m = 0; m < 4; ++m)
    #pragma unroll
    for (int n = 0; n < 4; ++n) acc[m][n] = (f32x4){0.f, 0.f, 0.f, 0.f};

  // prologue: two stages in flight; wait for the first, keep the second flying
  stage(0, 0);
  stage(1, 1);
  __builtin_amdgcn_sched_barrier(0);
  asm volatile("s_waitcnt vmcnt(4)" ::: "memory");
  __builtin_amdgcn_s_barrier();
  __builtin_amdgcn_sched_barrier(0);

  for (int t = 0; t < 8; ++t) {
    const int cur = t % 3;
    if (t + 2 < 8) stage(t + 2, (t + 2) % 3);    // deep prefetch (2 steps ahead)
    f16x8 a[4], b[4];
    #pragma unroll
    for (int m = 0; m < 4; ++m)
      a[m] = *(const f16x8*)&AS(cur)[(((wr << 2) + m) << 9) + js8];
    #pragma unroll
    for (int n = 0; n < 4; ++n)
      b[n] = *(const f16x8*)&BS(cur)[(((wc << 2) + n) << 9) + js8];
    #pragma unroll
    for (int m = 0; m < 4; ++m)
      #pragma unroll
      for (int n = 0; n < 4; ++n)
        acc[m][n] = __builtin_amdgcn_mfma_f32_16x16x32_f16(a[m], b[n], acc[m][n], 0, 0, 0);
    // counted-vmcnt barrier: stage(t+1) complete, stage(t+2) stays in flight
    __builtin_amdgcn_sched_barrier(0);
    if (t < 6) {
      asm volatile("s_waitcnt vmcnt(4)" ::: "memory");
    } else {
      asm volatile("s_waitcnt vmcnt(0)" ::: "memory");
    }
    __builtin_amdgcn_s_barrier();
    __builtin_amdgcn_sched_barrier(0);
  }

  // ---- epilogue v2 (R9-verified): local 4-col fold + one xor-1 butterfly +
  // swizzled LDS-arena scatter/gather ----
  float4* arena = (float4*)shm;              // 128*16*16B = 32 KB of 48
  float cnv[4];
  #pragma unroll
  for (int n = 0; n < 4; ++n) cnv[n] = cn2q[nb * 128 + wc * 64 + n * 16 + fr];

  #pragma unroll
  for (int m = 0; m < 4; ++m)
    #pragma unroll
    for (int r = 0; r < 4; ++r) {
      float v1 = __builtin_inff(), c1 = 1.0e9f, v2 = __builtin_inff(), c2 = 1.0e9f;
      #pragma unroll
      for (int n = 0; n < 4; ++n) {          // ascending col: < keeps first-min
        const float sv = fmaf(-2.f, acc[m][n][r], cnv[n]);
        const float cf = (float)(nb * 128 + wc * 64 + n * 16 + fr);
        if (sv < v1) { v2 = v1; c2 = c1; v1 = sv; c1 = cf; }
        else if (sv < v2) { v2 = sv; c2 = cf; }
      }
      // one butterfly round: merge partner fr^1 (cols disjoint)
      float w1 = __shfl_xor(v1, 1), d1 = __shfl_xor(c1, 1);
      float w2 = __shfl_xor(v2, 1), d2 = __shfl_xor(c2, 1);
      merge_top2(v1, c1, v2, c2, w1, d1, w2, d2);
      if ((fr & 1) == 0) {
        const int row128 = wr * 64 + m * 16 + fg * 4 + r;
        const int slot = (wc * 8 + (fr >> 1) + row128) & 15;   // bank swizzle
        arena[row128 * 16 + slot] = make_float4(v1, c1, v2, c2);
      }
    }
  __syncthreads();

  if (tid < 128) {
    float4 g0 = arena[tid * 16 + (tid & 15)];                  // logical slot 0
    float v1 = g0.x, c1 = g0.y, v2 = g0.z, c2 = g0.w;
    #pragma unroll
    for (int s = 1; s < 16; ++s) {
      float4 g = arena[tid * 16 + ((s + tid) & 15)];           // logical slot s
      merge_top2(v1, c1, v2, c2, g.x, g.y, g.z, g.w);
    }
    top2[(row0 + tid) * 8 + nb] = make_float4(v1, c1, v2, c2);
  }
  #undef AS
  #undef BS
}

// ---------------------------------------------------------------------------
// merge 8 per-block top2 partials per row -> index + flag list
// ---------------------------------------------------------------------------
__global__ __launch_bounds__(256) void rvq_reduce(
    const float4* __restrict__ top2, float* __restrict__ idx_out,
    int* __restrict__ list, int* __restrict__ cnt, int level)
{
  const int row = blockIdx.x * 256 + threadIdx.x;
  const float4* p = top2 + (size_t)row * 8;
  float4 f = p[0];
  float v1 = f.x, c1 = f.y, v2 = f.z, c2 = f.w;
  #pragma unroll
  for (int i = 1; i < 8; ++i) {                 // nb ascending = col ascending
    float4 g = p[i];
    merge_top2(v1, c1, v2, c2, g.x, g.y, g.z, g.w);
  }
  idx_out[(size_t)row * NQ + level] = c1;
  if (v2 - v1 <= TAU) {
    int q = atomicAdd(cnt + level, 1);
    list[q] = row;
  }
}

// ---------------------------------------------------------------------------
// exact fp32 re-argmin for flagged rows (full 1024-code scan)
// ---------------------------------------------------------------------------
__global__ __launch_bounds__(256) void rvq_cleanup(
    const float* __restrict__ src, const float* __restrict__ cbq,
    const float* __restrict__ cn2q, const int* __restrict__ list,
    const int* __restrict__ cnt, float* __restrict__ idx_out, int level)
{
  __shared__ __align__(16) float rsh[DD];
  __shared__ float wmin[4];
  __shared__ int wcol[4];
  const int tid = threadIdx.x;
  const int n = cnt[level];
  for (int it = blockIdx.x; it < n; it += gridDim.x) {
    const int row = list[it];
    __syncthreads();
    rsh[tid] = src[(size_t)row * DD + tid];
    __syncthreads();
    float bv = __builtin_inff(); int bc = 1 << 29;
    #pragma unroll
    for (int cc4 = 0; cc4 < 4; ++cc4) {
      const int c = cc4 * 256 + tid;
      const float4* ep = (const float4*)(cbq + (size_t)c * DD);
      float dot = 0.f;
      #pragma unroll 8
      for (int k4 = 0; k4 < 64; ++k4) {
        float4 e4 = ep[k4];
        float4 r4 = *(const float4*)&rsh[k4 * 4];
        dot = fmaf(r4.x, e4.x, dot);
        dot = fmaf(r4.y, e4.y, dot);
        dot = fmaf(r4.z, e4.z, dot);
        dot = fmaf(r4.w, e4.w, dot);
      }
      float s = fmaf(-2.f, dot, cn2q[c]);
      if (s < bv || (s == bv && c < bc)) { bv = s; bc = c; }
    }
    #pragma unroll
    for (int mk = 1; mk < 64; mk <<= 1) {
      float ov = __shfl_xor(bv, mk); int oc = __shfl_xor(bc, mk);
      if (ov < bv || (ov == bv && oc < bc)) { bv = ov; bc = oc; }
    }
    if ((tid & 63) == 0) { wmin[tid >> 6] = bv; wcol[tid >> 6] = bc; }
    __syncthreads();
    if (tid == 0) {
      float v = wmin[0]; int c = wcol[0];
      #pragma unroll
      for (int w = 1; w < 4; ++w)
        if (wmin[w] < v || (wmin[w] == v && wcol[w] < c)) { v = wmin[w]; c = wcol[w]; }
      idx_out[(size_t)row * NQ + level] = (float)c;
    }
  }
}

// ---------------------------------------------------------------------------
// residual update + fused loss: rn = src - e[idx]; levels 0-6: write res +
// fp16 hi split; level 7: write quantized_out = x - rn.  Per-block loss
// partial accumulated straight into loss_out[b][level] via one atomicAdd
// (1024 adds per cell; fp-order noise ~1e-5 << threshold).
// ---------------------------------------------------------------------------
__global__ __launch_bounds__(256) void rvq_update_split(
    const float* __restrict__ x, const float* __restrict__ src,
    float* __restrict__ res, const float* __restrict__ cbq,
    const float* __restrict__ idx_f, u16* __restrict__ rsplit,
    float* __restrict__ loss_out, int level)
{
  const int tid = threadIdx.x;
  const size_t row = (size_t)blockIdx.x * 4 + (tid >> 6);
  const int seg = (tid & 63) << 2;
  const int idx = (int)idx_f[row * NQ + level];
  const float4 e = *reinterpret_cast<const float4*>(cbq + (size_t)idx * DD + seg);
  const float4 r = *reinterpret_cast<const float4*>(src + row * DD + seg);
  float4 rn = make_float4(r.x - e.x, r.y - e.y, r.z - e.z, r.w - e.w);
  if (level < 7) {
    *reinterpret_cast<float4*>(res + row * DD + seg) = rn;
    ushort4 h; hi4h(rn, h);
    *(ushort4*)(rsplit + row * 256 + seg) = h;
  } else {
    const float4 xv = *reinterpret_cast<const float4*>(x + row * DD + seg);
    *reinterpret_cast<float4*>(res + row * DD + seg) =
        make_float4(xv.x - rn.x, xv.y - rn.y, xv.z - rn.z, xv.w - rn.w);
  }
  float p = rn.x * rn.x + rn.y * rn.y + rn.z * rn.z + rn.w * rn.w;
  #pragma unroll
  for (int mm = 1; mm < 64; mm <<= 1) p += __shfl_xor(p, mm);
  __shared__ float w4[4];
  if ((tid & 63) == 0) w4[tid >> 6] = p;
  __syncthreads();
  if (tid == 0) {
    const int b = (int)(row >> 12);            // 4096 rows per batch elem
    atomicAdd(loss_out + b * NQ + level,
              (w4[0] + w4[1] + w4[2] + w4[3]) * (1.0f / 1048576.0f));
  }
}

extern "C" void kernel_launch(void* const* d_in, const int* in_sizes, int n_in,
                              void* d_out, int out_size, void* d_ws, size_t ws_size,
                              hipStream_t stream) {
  const float* x  = (const float*)d_in[0];  // [8,4096,256]
  const float* cb = (const float*)d_in[1];  // [8,1024,256]
  float* out = (float*)d_out;

  // d_out layout (floats): quantized [ROWS*DD] | indices [ROWS*NQ] | losses [NB*NQ]
  float* res      = out;                    // residual shares quantized region
  float* out_idx  = out + (size_t)ROWS * DD;
  float* out_loss = out_idx + (size_t)ROWS * NQ;

  // workspace (~26 MB)
  char* w = (char*)d_ws;
  u16* rsplit = (u16*)w;                         w += (size_t)ROWS * 256 * 2;      // 16 MB (fp16 hi)
  u16* esp = (u16*)w;                            w += (size_t)NQ * CC * 256 * 2;   // 4 MB (fp16 hi)
  float4* top2 = (float4*)w;                     w += (size_t)ROWS * 8 * 16;       // 4 MB
  int* list = (int*)w;                           w += (size_t)NQ * ROWS * 4;       // 1 MB
  float* cn2 = (float*)w;                        w += (size_t)NQ * CC * 4;
  int* cnt = (int*)w;                            w += 64;

  rvq_pre<<<10240, 256, 0, stream>>>(x, cb, rsplit, esp, cnt, out_loss);
  rvq_norms<<<2048, 256, 0, stream>>>(cb, cn2);

  for (int q = 0; q < NQ; ++q) {
    const float* srcres = q ? res : x;
    const size_t eo = (size_t)q * CC * DD;
    rvq_gemm97<<<2048, 256, 0, stream>>>(
        rsplit, esp + (size_t)q * CC * 256, cn2 + (size_t)q * CC, top2);
    rvq_reduce<<<128, 256, 0, stream>>>(top2, out_idx, list + (size_t)q * ROWS, cnt, q);
    rvq_cleanup<<<256, 256, 0, stream>>>(
        srcres, cb + eo, cn2 + (size_t)q * CC, list + (size_t)q * ROWS, cnt, out_idx, q);
    rvq_update_split<<<ROWS / 4, 256, 0, stream>>>(
        x, srcres, res, cb + eo, out_idx, rsplit, out_loss, q);
  }
}

// Round 15
// 783.324 us; speedup vs baseline: 1.5177x; 1.5177x over previous
//
#include <hip/hip_runtime.h>
#include <math.h>

#define NB 8
#define NN 4096
#define DD 256
#define CC 1024
#define NQ 8
#define ROWS (NB*NN)        // 32768
// fp16 1-pass: score = cn2 - 2*hi_a·hi_e, K=256.
// Dropped terms (hi_a·lo_e + lo_a·e): pair-difference score err std ~9e-3.
// TAU = 0.0625 ~ 7 sigma; flagged rows get exact fp32 re-argmin.
#define TAU 0.0625f

typedef unsigned short u16;
typedef __attribute__((ext_vector_type(8))) _Float16 f16x8;  // 8 f16 (4 VGPRs)
typedef __attribute__((ext_vector_type(4))) float f32x4;

// ---- exact RNE fp32->fp16 helpers (v_cvt_f16_f32 is RNE) ----
__device__ __forceinline__ u16 f2h(float f) {
  _Float16 h = (_Float16)f;
  return __builtin_bit_cast(u16, h);
}
__device__ __forceinline__ void hi4h(float4 f, ushort4& h) {
  h.x = f2h(f.x); h.y = f2h(f.y); h.z = f2h(f.z); h.w = f2h(f.w);
}

// merge candidate pair (w1,d1)<=(w2,d2) into running sorted top-2
__device__ __forceinline__ void merge_top2(float& v1, float& c1, float& v2, float& c2,
                                           float w1, float d1, float w2, float d2) {
  if (w1 < v1 || (w1 == v1 && d1 < c1)) {
    float nv2, nc2;
    if (v1 < w2 || (v1 == w2 && c1 < d2)) { nv2 = v1; nc2 = c1; }
    else                                  { nv2 = w2; nc2 = d2; }
    v1 = w1; c1 = d1; v2 = nv2; c2 = nc2;
  } else {
    if (w1 < v2 || (w1 == v2 && d1 < c2)) { v2 = w1; c2 = d1; }
  }
}

__device__ __forceinline__ void gload16(const void* g, void* l) {
  __builtin_amdgcn_global_load_lds(
      (const __attribute__((address_space(1))) unsigned int*)g,
      (__attribute__((address_space(3))) unsigned int*)l, 16, 0, 0);
}

// ---------------------------------------------------------------------------
// fused preamble: x -> rsplit [ROWS][256] fp16 hi  (blocks 0..8191)
//                 cb -> esp [NQ*CC][256] fp16 hi   (blocks 8192..10239)
// block 0 also zeroes cnt.
// ---------------------------------------------------------------------------
__global__ __launch_bounds__(256) void rvq_pre(
    const float* __restrict__ x, const float* __restrict__ cb,
    u16* __restrict__ rsplit, u16* __restrict__ esp, int* __restrict__ cnt)
{
  if (blockIdx.x == 0 && threadIdx.x < NQ) cnt[threadIdx.x] = 0;
  const size_t f = (size_t)blockIdx.x * 256 + threadIdx.x;
  if (f < (size_t)ROWS * 64) {                 // x region: 2M float4
    const size_t row = f >> 6;
    const int c4 = (int)(f & 63) << 2;
    float4 v = ((const float4*)x)[f];
    ushort4 h; hi4h(v, h);
    *(ushort4*)(rsplit + row * 256 + c4) = h;
  } else {                                     // cb region: 512K float4
    const size_t g = f - (size_t)ROWS * 64;
    const size_t row = g >> 6;
    const int c4 = (int)(g & 63) << 2;
    float4 v = ((const float4*)cb)[g];
    ushort4 h; hi4h(v, h);
    *(ushort4*)(esp + row * 256 + c4) = h;
  }
}

// ---------------------------------------------------------------------------
// ||e_c||^2 for all levels (fp32), one wave per code
// ---------------------------------------------------------------------------
__global__ __launch_bounds__(256) void rvq_norms(
    const float* __restrict__ cb, float* __restrict__ cn2)
{
  const int tid = threadIdx.x;
  const size_t code = (size_t)blockIdx.x * 4 + (tid >> 6);
  const int l = tid & 63;
  const float4 v = *reinterpret_cast<const float4*>(cb + code * DD + l * 4);
  float s = v.x * v.x + v.y * v.y + v.z * v.z + v.w * v.w;
  #pragma unroll
  for (int mm = 1; mm < 64; mm <<= 1) s += __shfl_xor(s, mm);
  if (l == 0) cn2[code] = s;
}

// ---------------------------------------------------------------------------
// MFMA GEMM + per-block top2.  fp16 hi x hi, K=256, BK=32, 8 steps.
// R12-verified: BM=128 BN=128, acc[4][4], triple-buffer gload_lds, counted
// vmcnt(4), T2 swizzle (conflicts==0), XCD decode, epilogue v2.
// ---------------------------------------------------------------------------
__global__ __launch_bounds__(256) void rvq_gemm97(
    const u16* __restrict__ rsplit,   // [ROWS][256]  fp16 hi
    const u16* __restrict__ esp,      // [CC][256]    fp16 hi (level)
    const float* __restrict__ cn2q,   // [CC]         (level)
    float4* __restrict__ top2)        // [ROWS][8]
{
  // single 48 KB arena: As[3] at 0..24KB, Bs[3] at 24..48KB; epilogue reuses
  __shared__ __align__(16) u16 shm[24576];
  #define AS(c) (shm + (c) * 4096)
  #define BS(c) (shm + 12288 + (c) * 4096)

  const int tid = threadIdx.x;
  const int lane = tid & 63;
  const int wv = tid >> 6;
  const int wr = wv >> 1, wc = wv & 1;
  const int fr = lane & 15, fg = lane >> 4;
  // XCD-locality decode: bid = mbhi*64 + nb*8 + (mb%8)
  const int bid = blockIdx.x;
  const int mb = ((bid >> 6) << 3) | (bid & 7);
  const int nb = (bid >> 3) & 7;
  const size_t row0 = (size_t)mb * 128;

  // ---- T2: swizzled per-lane source slot for staging (LDS dest is linear) ----
  const int jl = lane ^ ((lane >> 3) & 3);   // logical slot this lane must fetch
  const int lrow = jl >> 2;                  // row within 16-row region
  const int lc4 = jl & 3;                    // 16B k-chunk within row

  // ---- T2: swizzled LDS offset for fragment reads (u16 units) ----
  const int j = (fr << 2) + fg;              // logical slot (row fr, k-chunk fg)
  const int js8 = (j ^ ((j >> 3) & 3)) << 3; // swizzled, *8 u16 per 16B slot

  auto stage = [&](int t, int cur) {
    const int o = (t & 7) << 5;               // k-chunk (u16) within 256
    #pragma unroll
    for (int r = 0; r < 2; ++r) {
      const int r0 = ((r << 2) + wv) << 4;                    // region first row
      const int grow = r0 + lrow;
      gload16(rsplit + (row0 + grow) * 256 + o + (lc4 << 3), AS(cur) + r0 * 32);
      gload16(esp + (size_t)(nb * 128 + grow) * 256 + o + (lc4 << 3), BS(cur) + r0 * 32);
    }
  };

  f32x4 acc[4][4];
  #pragma unroll
  for (int m = 0; m < 4; ++m)
    #pragma unroll
    for (int n = 0; n < 4; ++n) acc[m][n] = (f32x4){0.f, 0.f, 0.f, 0.f};

  // prologue: two stages in flight; wait for the first, keep the second flying
  stage(0, 0);
  stage(1, 1);
  __builtin_amdgcn_sched_barrier(0);
  asm volatile("s_waitcnt vmcnt(4)" ::: "memory");
  __builtin_amdgcn_s_barrier();
  __builtin_amdgcn_sched_barrier(0);

  for (int t = 0; t < 8; ++t) {
    const int cur = t % 3;
    if (t + 2 < 8) stage(t + 2, (t + 2) % 3);    // deep prefetch (2 steps ahead)
    f16x8 a[4], b[4];
    #pragma unroll
    for (int m = 0; m < 4; ++m)
      a[m] = *(const f16x8*)&AS(cur)[(((wr << 2) + m) << 9) + js8];
    #pragma unroll
    for (int n = 0; n < 4; ++n)
      b[n] = *(const f16x8*)&BS(cur)[(((wc << 2) + n) << 9) + js8];
    #pragma unroll
    for (int m = 0; m < 4; ++m)
      #pragma unroll
      for (int n = 0; n < 4; ++n)
        acc[m][n] = __builtin_amdgcn_mfma_f32_16x16x32_f16(a[m], b[n], acc[m][n], 0, 0, 0);
    // counted-vmcnt barrier: stage(t+1) complete, stage(t+2) stays in flight
    __builtin_amdgcn_sched_barrier(0);
    if (t < 6) {
      asm volatile("s_waitcnt vmcnt(4)" ::: "memory");
    } else {
      asm volatile("s_waitcnt vmcnt(0)" ::: "memory");
    }
    __builtin_amdgcn_s_barrier();
    __builtin_amdgcn_sched_barrier(0);
  }

  // ---- epilogue v2 (R9-verified): local 4-col fold + one xor-1 butterfly +
  // swizzled LDS-arena scatter/gather ----
  float4* arena = (float4*)shm;              // 128*16*16B = 32 KB of 48
  float cnv[4];
  #pragma unroll
  for (int n = 0; n < 4; ++n) cnv[n] = cn2q[nb * 128 + wc * 64 + n * 16 + fr];

  #pragma unroll
  for (int m = 0; m < 4; ++m)
    #pragma unroll
    for (int r = 0; r < 4; ++r) {
      float v1 = __builtin_inff(), c1 = 1.0e9f, v2 = __builtin_inff(), c2 = 1.0e9f;
      #pragma unroll
      for (int n = 0; n < 4; ++n) {          // ascending col: < keeps first-min
        const float sv = fmaf(-2.f, acc[m][n][r], cnv[n]);
        const float cf = (float)(nb * 128 + wc * 64 + n * 16 + fr);
        if (sv < v1) { v2 = v1; c2 = c1; v1 = sv; c1 = cf; }
        else if (sv < v2) { v2 = sv; c2 = cf; }
      }
      // one butterfly round: merge partner fr^1 (cols disjoint)
      float w1 = __shfl_xor(v1, 1), d1 = __shfl_xor(c1, 1);
      float w2 = __shfl_xor(v2, 1), d2 = __shfl_xor(c2, 1);
      merge_top2(v1, c1, v2, c2, w1, d1, w2, d2);
      if ((fr & 1) == 0) {
        const int row128 = wr * 64 + m * 16 + fg * 4 + r;
        const int slot = (wc * 8 + (fr >> 1) + row128) & 15;   // bank swizzle
        arena[row128 * 16 + slot] = make_float4(v1, c1, v2, c2);
      }
    }
  __syncthreads();

  if (tid < 128) {
    float4 g0 = arena[tid * 16 + (tid & 15)];                  // logical slot 0
    float v1 = g0.x, c1 = g0.y, v2 = g0.z, c2 = g0.w;
    #pragma unroll
    for (int s = 1; s < 16; ++s) {
      float4 g = arena[tid * 16 + ((s + tid) & 15)];           // logical slot s
      merge_top2(v1, c1, v2, c2, g.x, g.y, g.z, g.w);
    }
    top2[(row0 + tid) * 8 + nb] = make_float4(v1, c1, v2, c2);
  }
  #undef AS
  #undef BS
}

// ---------------------------------------------------------------------------
// merge 8 per-block top2 partials per row -> index + flag list
// ---------------------------------------------------------------------------
__global__ __launch_bounds__(256) void rvq_reduce(
    const float4* __restrict__ top2, float* __restrict__ idx_out,
    int* __restrict__ list, int* __restrict__ cnt, int level)
{
  const int row = blockIdx.x * 256 + threadIdx.x;
  const float4* p = top2 + (size_t)row * 8;
  float4 f = p[0];
  float v1 = f.x, c1 = f.y, v2 = f.z, c2 = f.w;
  #pragma unroll
  for (int i = 1; i < 8; ++i) {                 // nb ascending = col ascending
    float4 g = p[i];
    merge_top2(v1, c1, v2, c2, g.x, g.y, g.z, g.w);
  }
  idx_out[(size_t)row * NQ + level] = c1;
  if (v2 - v1 <= TAU) {
    int q = atomicAdd(cnt + level, 1);
    list[q] = row;
  }
}

// ---------------------------------------------------------------------------
// exact fp32 re-argmin for flagged rows (full 1024-code scan)
// ---------------------------------------------------------------------------
__global__ __launch_bounds__(256) void rvq_cleanup(
    const float* __restrict__ src, const float* __restrict__ cbq,
    const float* __restrict__ cn2q, const int* __restrict__ list,
    const int* __restrict__ cnt, float* __restrict__ idx_out, int level)
{
  __shared__ __align__(16) float rsh[DD];
  __shared__ float wmin[4];
  __shared__ int wcol[4];
  const int tid = threadIdx.x;
  const int n = cnt[level];
  for (int it = blockIdx.x; it < n; it += gridDim.x) {
    const int row = list[it];
    __syncthreads();
    rsh[tid] = src[(size_t)row * DD + tid];
    __syncthreads();
    float bv = __builtin_inff(); int bc = 1 << 29;
    #pragma unroll
    for (int cc4 = 0; cc4 < 4; ++cc4) {
      const int c = cc4 * 256 + tid;
      const float4* ep = (const float4*)(cbq + (size_t)c * DD);
      float dot = 0.f;
      #pragma unroll 8
      for (int k4 = 0; k4 < 64; ++k4) {
        float4 e4 = ep[k4];
        float4 r4 = *(const float4*)&rsh[k4 * 4];
        dot = fmaf(r4.x, e4.x, dot);
        dot = fmaf(r4.y, e4.y, dot);
        dot = fmaf(r4.z, e4.z, dot);
        dot = fmaf(r4.w, e4.w, dot);
      }
      float s = fmaf(-2.f, dot, cn2q[c]);
      if (s < bv || (s == bv && c < bc)) { bv = s; bc = c; }
    }
    #pragma unroll
    for (int mk = 1; mk < 64; mk <<= 1) {
      float ov = __shfl_xor(bv, mk); int oc = __shfl_xor(bc, mk);
      if (ov < bv || (ov == bv && oc < bc)) { bv = ov; bc = oc; }
    }
    if ((tid & 63) == 0) { wmin[tid >> 6] = bv; wcol[tid >> 6] = bc; }
    __syncthreads();
    if (tid == 0) {
      float v = wmin[0]; int c = wcol[0];
      #pragma unroll
      for (int w = 1; w < 4; ++w)
        if (wmin[w] < v || (wmin[w] == v && wcol[w] < c)) { v = wmin[w]; c = wcol[w]; }
      idx_out[(size_t)row * NQ + level] = (float)c;
    }
  }
}

// ---------------------------------------------------------------------------
// residual update: rn = src - e[idx]; levels 0-6: write res + fp16 hi split;
// level 7: write quantized_out = x - rn. Loss partials per 4-row block.
// ---------------------------------------------------------------------------
__global__ __launch_bounds__(256) void rvq_update_split(
    const float* __restrict__ x, const float* __restrict__ src,
    float* __restrict__ res, const float* __restrict__ cbq,
    const float* __restrict__ idx_f, u16* __restrict__ rsplit,
    float* __restrict__ partials, int level)
{
  const int tid = threadIdx.x;
  const size_t row = (size_t)blockIdx.x * 4 + (tid >> 6);
  const int seg = (tid & 63) << 2;
  const int idx = (int)idx_f[row * NQ + level];
  const float4 e = *reinterpret_cast<const float4*>(cbq + (size_t)idx * DD + seg);
  const float4 r = *reinterpret_cast<const float4*>(src + row * DD + seg);
  float4 rn = make_float4(r.x - e.x, r.y - e.y, r.z - e.z, r.w - e.w);
  if (level < 7) {
    *reinterpret_cast<float4*>(res + row * DD + seg) = rn;
    ushort4 h; hi4h(rn, h);
    *(ushort4*)(rsplit + row * 256 + seg) = h;
  } else {
    const float4 xv = *reinterpret_cast<const float4*>(x + row * DD + seg);
    *reinterpret_cast<float4*>(res + row * DD + seg) =
        make_float4(xv.x - rn.x, xv.y - rn.y, xv.z - rn.z, xv.w - rn.w);
  }
  float p = rn.x * rn.x + rn.y * rn.y + rn.z * rn.z + rn.w * rn.w;
  #pragma unroll
  for (int mm = 1; mm < 64; mm <<= 1) p += __shfl_xor(p, mm);
  __shared__ float w4[4];
  if ((tid & 63) == 0) w4[tid >> 6] = p;
  __syncthreads();
  if (tid == 0) partials[blockIdx.x] = w4[0] + w4[1] + w4[2] + w4[3];
}

__global__ __launch_bounds__(256) void rvq_loss(
    const float* __restrict__ partials, float* __restrict__ loss_out, int level)
{
  const int b = blockIdx.x;
  const int tid = threadIdx.x;
  float s = 0.f;
  for (int i = tid; i < 1024; i += 256) s += partials[b * 1024 + i];
  #pragma unroll
  for (int mm = 1; mm < 64; mm <<= 1) s += __shfl_xor(s, mm);
  __shared__ float w4[4];
  if ((tid & 63) == 0) w4[tid >> 6] = s;
  __syncthreads();
  if (tid == 0)
    loss_out[b * NQ + level] = (w4[0] + w4[1] + w4[2] + w4[3]) * (1.0f / 1048576.0f);
}

extern "C" void kernel_launch(void* const* d_in, const int* in_sizes, int n_in,
                              void* d_out, int out_size, void* d_ws, size_t ws_size,
                              hipStream_t stream) {
  const float* x  = (const float*)d_in[0];  // [8,4096,256]
  const float* cb = (const float*)d_in[1];  // [8,1024,256]
  float* out = (float*)d_out;

  // d_out layout (floats): quantized [ROWS*DD] | indices [ROWS*NQ] | losses [NB*NQ]
  float* res      = out;                    // residual shares quantized region
  float* out_idx  = out + (size_t)ROWS * DD;
  float* out_loss = out_idx + (size_t)ROWS * NQ;

  // workspace (~26 MB)
  char* w = (char*)d_ws;
  u16* rsplit = (u16*)w;                         w += (size_t)ROWS * 256 * 2;      // 16 MB (fp16 hi)
  u16* esp = (u16*)w;                            w += (size_t)NQ * CC * 256 * 2;   // 4 MB (fp16 hi)
  float4* top2 = (float4*)w;                     w += (size_t)ROWS * 8 * 16;       // 4 MB
  int* list = (int*)w;                           w += (size_t)NQ * ROWS * 4;       // 1 MB
  float* cn2 = (float*)w;                        w += (size_t)NQ * CC * 4;
  float* partials = (float*)w;                   w += (size_t)(ROWS / 4) * 4;
  int* cnt = (int*)w;                            w += 64;

  rvq_pre<<<10240, 256, 0, stream>>>(x, cb, rsplit, esp, cnt);
  rvq_norms<<<2048, 256, 0, stream>>>(cb, cn2);

  for (int q = 0; q < NQ; ++q) {
    const float* srcres = q ? res : x;
    const size_t eo = (size_t)q * CC * DD;
    rvq_gemm97<<<2048, 256, 0, stream>>>(
        rsplit, esp + (size_t)q * CC * 256, cn2 + (size_t)q * CC, top2);
    rvq_reduce<<<128, 256, 0, stream>>>(top2, out_idx, list + (size_t)q * ROWS, cnt, q);
    rvq_cleanup<<<256, 256, 0, stream>>>(
        srcres, cb + eo, cn2 + (size_t)q * CC, list + (size_t)q * ROWS, cnt, out_idx, q);
    rvq_update_split<<<ROWS / 4, 256, 0, stream>>>(
        x, srcres, res, cb + eo, out_idx, rsplit, partials, q);
    rvq_loss<<<NB, 256, 0, stream>>>(partials, out_loss, q);
  }
}